// Round 4
// baseline (8918.118 us; speedup 1.0000x reference)
//
#include <hip/hip_runtime.h>
#include <hip/hip_bf16.h>
#include <math.h>

typedef unsigned short u16;

#define BATCH 16
#define NTOK  3136
#define CHN   512
#define NH    8
#define HD    64
#define HHW   56
#define NAG   144
#define PS    12

__device__ __forceinline__ float b2f(u16 u) {
    unsigned int x = ((unsigned int)u) << 16;
    float f;
    __builtin_memcpy(&f, &x, 4);
    return f;
}
__device__ __forceinline__ u16 f2b(float f) {
    unsigned int x;
    __builtin_memcpy(&x, &f, 4);
    unsigned int lsb = (x >> 16) & 1u;
    x += 0x7fffu + lsb;            // round-to-nearest-even (finite values)
    return (u16)(x >> 16);
}

// load 4 consecutive elements as floats
__device__ __forceinline__ void load4(const float* p, float* d) {
    float4 v = *reinterpret_cast<const float4*>(p);
    d[0] = v.x; d[1] = v.y; d[2] = v.z; d[3] = v.w;
}
__device__ __forceinline__ void load4(const u16* p, float* d) {
    ushort4 v = *reinterpret_cast<const ushort4*>(p);
    d[0] = b2f(v.x); d[1] = b2f(v.y); d[2] = b2f(v.z); d[3] = b2f(v.w);
}
__device__ __forceinline__ void store1(float* p, float v) { *p = v; }
__device__ __forceinline__ void store1(u16* p, float v)   { *p = f2b(v); }

// ---------------------------------------------------------------------------
// out[m,n] = A[m,:] . W[n,:] (+ optional bias).  A: M x 512 (fp32 or bf16),
// W: fp32 rows of 512 (caller pre-offsets), out: M x 512 (fp32 or bf16).
// Grid: (M/64, 8). 64x64 tile, 256 thr, 4x4 micro-tile, fp32 FMA.
// ---------------------------------------------------------------------------
template <typename AT, typename OT>
__global__ __launch_bounds__(256) void gemm64_kernel(
    const AT* __restrict__ A, const float* __restrict__ W,
    const float* __restrict__ bias, OT* __restrict__ out)
{
    __shared__ float As[64][17];
    __shared__ float Bs[64][17];
    const int tid = threadIdx.x;
    const int ty = tid >> 4, tx = tid & 15;
    const int m0 = blockIdx.x * 64;
    const int n0 = blockIdx.y * 64;
    const int lr = tid >> 2;
    const int lc = (tid & 3) << 2;
    float acc[4][4] = {};

    for (int k0 = 0; k0 < 512; k0 += 16) {
        float av[4], bv[4];
        load4(&A[(size_t)(m0 + lr) * 512 + k0 + lc], av);
        load4(&W[(size_t)(n0 + lr) * 512 + k0 + lc], bv);
        As[lr][lc + 0] = av[0]; As[lr][lc + 1] = av[1];
        As[lr][lc + 2] = av[2]; As[lr][lc + 3] = av[3];
        Bs[lr][lc + 0] = bv[0]; Bs[lr][lc + 1] = bv[1];
        Bs[lr][lc + 2] = bv[2]; Bs[lr][lc + 3] = bv[3];
        __syncthreads();
        #pragma unroll
        for (int kk = 0; kk < 16; ++kk) {
            float a[4], b[4];
            #pragma unroll
            for (int i = 0; i < 4; ++i) a[i] = As[ty * 4 + i][kk];
            #pragma unroll
            for (int j = 0; j < 4; ++j) b[j] = Bs[tx * 4 + j][kk];
            #pragma unroll
            for (int i = 0; i < 4; ++i)
                #pragma unroll
                for (int j = 0; j < 4; ++j)
                    acc[i][j] += a[i] * b[j];
        }
        __syncthreads();
    }

    #pragma unroll
    for (int i = 0; i < 4; ++i) {
        const int m = m0 + ty * 4 + i;
        #pragma unroll
        for (int j = 0; j < 4; ++j) {
            const int col = n0 + tx * 4 + j;
            float r = acc[i][j];
            if (bias) r += bias[col];
            store1(&out[(size_t)m * 512 + col], r);
        }
    }
}

// ---------------------------------------------------------------------------
// Adaptive avg-pool x (b,56,56,c) fp32 -> x_pool (b,144,c) bf16.
// (Pooling is linear; agent = pool(x) @ Wq^T computed by gemm64 after.)
// ---------------------------------------------------------------------------
__global__ __launch_bounds__(256) void pool_x_kernel(
    const float* __restrict__ x, u16* __restrict__ x_pool)
{
    const int b = blockIdx.x, pq = blockIdx.y;
    const int p = pq / PS, qq = pq % PS;
    const int sp_ = (p * HHW) / PS, ep_ = ((p + 1) * HHW + PS - 1) / PS;
    const int sq_ = (qq * HHW) / PS, eq_ = ((qq + 1) * HHW + PS - 1) / PS;
    const float inv = 1.0f / (float)((ep_ - sp_) * (eq_ - sq_));
    for (int ch = threadIdx.x; ch < CHN; ch += 256) {
        float acc = 0.f;
        for (int y = sp_; y < ep_; ++y)
            for (int xx = sq_; xx < eq_; ++xx)
                acc += x[((size_t)b * NTOK + y * HHW + xx) * CHN + ch];
        x_pool[((size_t)b * NAG + pq) * CHN + ch] = f2b(acc * inv);
    }
}

// ---------------------------------------------------------------------------
// Stage-1 attention. One block per (b,h,a). All attention tensors bf16.
// scores[n] = (0.125*agent_ha) . k_hn ; softmax ; agent_v = p @ v_h
// ---------------------------------------------------------------------------
__global__ __launch_bounds__(256) void stage1_kernel(
    const u16* __restrict__ k, const u16* __restrict__ v,
    const u16* __restrict__ agent, u16* __restrict__ agent_v)
{
    __shared__ float sc[NTOK];
    __shared__ float red[256];
    __shared__ float afrag[HD];
    __shared__ float outb[HD];

    const int gid = blockIdx.x;
    const int a = gid % NAG;
    const int bh = gid / NAG;
    const int h = bh % NH;
    const int b = bh / NH;
    const int tid = threadIdx.x;

    if (tid < HD)
        afrag[tid] = b2f(agent[((size_t)b * NAG + a) * CHN + h * HD + tid]) * 0.125f;
    __syncthreads();

    // pass 1: scores + local max
    float lmax = -1e30f;
    for (int j = tid; j < NTOK; j += 256) {
        const u16* kr = k + ((size_t)b * NTOK + j) * CHN + h * HD;
        const ushort4* kr4 = reinterpret_cast<const ushort4*>(kr);
        float s = 0.f;
        #pragma unroll
        for (int t4 = 0; t4 < 16; ++t4) {
            ushort4 kv = kr4[t4];
            s += afrag[t4 * 4 + 0] * b2f(kv.x) + afrag[t4 * 4 + 1] * b2f(kv.y)
               + afrag[t4 * 4 + 2] * b2f(kv.z) + afrag[t4 * 4 + 3] * b2f(kv.w);
        }
        sc[j] = s;
        lmax = fmaxf(lmax, s);
    }
    red[tid] = lmax;
    __syncthreads();
    for (int sdx = 128; sdx > 0; sdx >>= 1) {
        if (tid < sdx) red[tid] = fmaxf(red[tid], red[tid + sdx]);
        __syncthreads();
    }
    const float gmax = red[0];
    __syncthreads();

    // pass 2: exp + sum
    float lsum = 0.f;
    for (int j = tid; j < NTOK; j += 256) {
        float e = __expf(sc[j] - gmax);
        sc[j] = e;
        lsum += e;
    }
    red[tid] = lsum;
    __syncthreads();
    for (int sdx = 128; sdx > 0; sdx >>= 1) {
        if (tid < sdx) red[tid] += red[tid + sdx];
        __syncthreads();
    }
    const float ginv = 1.f / red[0];
    if (tid < HD) outb[tid] = 0.f;
    __syncthreads();

    // pass 3: weighted sum of V
    const int dim = tid & 63, g = tid >> 6;
    const u16* vbase = v + (size_t)b * NTOK * CHN + h * HD + dim;
    float acc = 0.f;
    for (int j = g; j < NTOK; j += 4)
        acc += sc[j] * b2f(vbase[(size_t)j * CHN]);
    atomicAdd(&outb[dim], acc);
    __syncthreads();
    if (tid < HD)
        agent_v[(((size_t)b * NH + h) * NAG + a) * HD + tid] = f2b(outb[tid] * ginv);
}

// ---------------------------------------------------------------------------
// Stage-2 attention + fused depthwise 3x3 conv residual.
// One 512-thread block per (b, query i); wave = head; channel = tid.
// q (bf16, in d_out), v (bf16, in d_out), dwc fp32; writes bf16 attn row into
// xattn (= x input buffer, dead after q-GEMM) — disjoint, race-free.
// ---------------------------------------------------------------------------
__global__ __launch_bounds__(512) void stage2_kernel(
    const u16* __restrict__ q,
    const u16* __restrict__ agent,
    const u16* __restrict__ agent_v,
    const u16* __restrict__ v,
    const float* __restrict__ dwc_w,
    const float* __restrict__ dwc_b,
    u16* __restrict__ xattn)
{
    __shared__ float qrow[CHN];
    __shared__ float sp[NH][NAG];

    const int bi = blockIdx.x;            // b*3136 + i
    const int b = bi / NTOK;
    const int i = bi % NTOK;
    const int tid = threadIdx.x;
    const int h = tid >> 6, dim = tid & 63;

    qrow[tid] = b2f(q[(size_t)bi * CHN + tid]) * 0.125f;
    __syncthreads();

    float s[3];
    #pragma unroll
    for (int slot = 0; slot < 3; ++slot) {
        const int a = dim + slot * 64;
        float acc = -1e30f;
        if (a < NAG) {
            const ushort4* ar = reinterpret_cast<const ushort4*>(
                &agent[((size_t)b * NAG + a) * CHN + h * HD]);
            acc = 0.f;
            #pragma unroll
            for (int t4 = 0; t4 < 16; ++t4) {
                ushort4 av = ar[t4];
                acc += qrow[h * HD + t4 * 4 + 0] * b2f(av.x) + qrow[h * HD + t4 * 4 + 1] * b2f(av.y)
                     + qrow[h * HD + t4 * 4 + 2] * b2f(av.z) + qrow[h * HD + t4 * 4 + 3] * b2f(av.w);
            }
        }
        s[slot] = acc;
    }
    float m = fmaxf(fmaxf(s[0], s[1]), s[2]);
    #pragma unroll
    for (int off = 32; off > 0; off >>= 1) m = fmaxf(m, __shfl_xor(m, off));
    float e0 = __expf(s[0] - m);
    float e1 = __expf(s[1] - m);
    float e2 = (dim < NAG - 128) ? __expf(s[2] - m) : 0.f;
    float lsum = e0 + e1 + e2;
    #pragma unroll
    for (int off = 32; off > 0; off >>= 1) lsum += __shfl_xor(lsum, off);
    const float inv = 1.f / lsum;
    sp[h][dim] = e0 * inv;
    sp[h][dim + 64] = e1 * inv;
    if (dim < NAG - 128) sp[h][dim + 128] = e2 * inv;
    __syncthreads();

    float outv = 0.f;
    const u16* avr = &agent_v[(((size_t)b * NH + h) * NAG) * HD + dim];
    #pragma unroll 4
    for (int a = 0; a < NAG; ++a) outv += sp[h][a] * b2f(avr[(size_t)a * HD]);

    // fused depthwise 3x3 SAME conv on v (+bias), channel = tid
    const int y = i / HHW, xx = i % HHW;
    float conv = dwc_b[tid];
    #pragma unroll
    for (int dy = -1; dy <= 1; ++dy) {
        const int yy = y + dy;
        if (yy < 0 || yy >= HHW) continue;
        #pragma unroll
        for (int dx = -1; dx <= 1; ++dx) {
            const int xc = xx + dx;
            if (xc < 0 || xc >= HHW) continue;
            conv += b2f(v[((size_t)b * NTOK + yy * HHW + xc) * CHN + tid])
                  * dwc_w[tid * 9 + (dy + 1) * 3 + (dx + 1)];
        }
    }

    xattn[(size_t)bi * CHN + tid] = f2b(outv + conv);
}

// ---------------------------------------------------------------------------
extern "C" void kernel_launch(void* const* d_in, const int* in_sizes, int n_in,
                              void* d_out, int out_size, void* d_ws, size_t ws_size,
                              hipStream_t stream)
{
    const float* x      = (const float*)d_in[0];
    const float* qkv_w  = (const float*)d_in[1];
    const float* proj_w = (const float*)d_in[2];
    const float* proj_b = (const float*)d_in[3];
    const float* dwc_w  = (const float*)d_in[4];
    const float* dwc_b  = (const float*)d_in[5];
    float* out = (float*)d_out;

    // d_out is 25,690,112 fp32 = 102,760,448 B. As bf16 scratch it exactly
    // holds k (25,690,112 u16) + v (25,690,112 u16). q overwrites k after
    // stage-1; the final fp32 proj output overwrites everything (k,q,v dead).
    const size_t nqkv = (size_t)BATCH * NTOK * CHN;       // 25,690,112
    u16* kq = (u16*)d_out;            // k, later q
    u16* vb = kq + nqkv;              // v
    // attn (bf16) goes into x's buffer (x dead after the q-GEMM; harness
    // restores inputs from pristine copies before every launch).
    u16* xattn = (u16*)d_in[0];

    // ws: x_pool + agent + agent_v, bf16, 3 x 2,359,296 B = 7,077,888 B.
    char* p = (char*)d_ws;
    u16* x_pool  = (u16*)p;  p += (size_t)BATCH * NAG * CHN * 2;
    u16* agent   = (u16*)p;  p += (size_t)BATCH * NAG * CHN * 2;
    u16* agent_v = (u16*)p;

    const float* Wq = qkv_w;
    const float* Wk = qkv_w + (size_t)512 * 512;
    const float* Wv = qkv_w + (size_t)1024 * 512;

    // 1. pooled x (pooling is linear: agent = pool(x) @ Wq^T)
    pool_x_kernel<<<dim3(BATCH, NAG), 256, 0, stream>>>(x, x_pool);
    // 2. agent = x_pool @ Wq^T   (M = 2304)
    gemm64_kernel<u16, u16><<<dim3(36, 8), 256, 0, stream>>>(x_pool, Wq, nullptr, agent);
    // 3. k = x @ Wk^T -> d_out lower half
    gemm64_kernel<float, u16><<<dim3(784, 8), 256, 0, stream>>>(x, Wk, nullptr, kq);
    // 4. v = x @ Wv^T -> d_out upper half
    gemm64_kernel<float, u16><<<dim3(784, 8), 256, 0, stream>>>(x, Wv, nullptr, vb);
    // 5. stage-1 attention
    stage1_kernel<<<BATCH * NH * NAG, 256, 0, stream>>>(kq, vb, agent, agent_v);
    // 6. q = x @ Wq^T -> d_out lower half (k dead)
    gemm64_kernel<float, u16><<<dim3(784, 8), 256, 0, stream>>>(x, Wq, nullptr, kq);
    // 7. stage-2 + depthwise conv -> xattn (x buffer; x dead afterwards)
    stage2_kernel<<<BATCH * NTOK, 512, 0, stream>>>(kq, agent, agent_v, vb, dwc_w, dwc_b, xattn);
    // 8. out = attn @ proj_w^T + proj_b -> d_out fp32 (q, v dead)
    gemm64_kernel<u16, float><<<dim3(784, 8), 256, 0, stream>>>(xattn, proj_w, proj_b, out);
}

// Round 5
// 5523.067 us; speedup vs baseline: 1.6147x; 1.6147x over previous
//
#include <hip/hip_runtime.h>
#include <hip/hip_bf16.h>
#include <math.h>

typedef unsigned short u16;

#define BATCH 16
#define NTOK  3136
#define CHN   512
#define NH    8
#define HD    64
#define HHW   56
#define NAG   144
#define PS    12

#define TK     64      // key tile for flash stage-1
#define KPITCH 66      // u16 pitch for Ks/Vs tiles (even -> 8B-aligned ushort4)

__device__ __forceinline__ float b2f(u16 u) {
    unsigned int x = ((unsigned int)u) << 16;
    float f;
    __builtin_memcpy(&f, &x, 4);
    return f;
}
__device__ __forceinline__ u16 f2b(float f) {
    unsigned int x;
    __builtin_memcpy(&x, &f, 4);
    unsigned int lsb = (x >> 16) & 1u;
    x += 0x7fffu + lsb;            // round-to-nearest-even (finite values)
    return (u16)(x >> 16);
}

// load 4 consecutive elements as floats
__device__ __forceinline__ void load4(const float* p, float* d) {
    float4 v = *reinterpret_cast<const float4*>(p);
    d[0] = v.x; d[1] = v.y; d[2] = v.z; d[3] = v.w;
}
__device__ __forceinline__ void load4(const u16* p, float* d) {
    ushort4 v = *reinterpret_cast<const ushort4*>(p);
    d[0] = b2f(v.x); d[1] = b2f(v.y); d[2] = b2f(v.z); d[3] = b2f(v.w);
}
__device__ __forceinline__ void store1(float* p, float v) { *p = v; }
__device__ __forceinline__ void store1(u16* p, float v)   { *p = f2b(v); }

// ---------------------------------------------------------------------------
// out[m,n] = A[m,:] . W[n,:] (+ optional bias).  A: M x 512 (fp32 or bf16),
// W: fp32 rows of 512 (caller pre-offsets), out: M x 512 (fp32 or bf16).
// Grid: (M/64, 8). 64x64 tile, 256 thr, 4x4 micro-tile, fp32 FMA.
// ---------------------------------------------------------------------------
template <typename AT, typename OT>
__global__ __launch_bounds__(256) void gemm64_kernel(
    const AT* __restrict__ A, const float* __restrict__ W,
    const float* __restrict__ bias, OT* __restrict__ out)
{
    __shared__ float As[64][17];
    __shared__ float Bs[64][17];
    const int tid = threadIdx.x;
    const int ty = tid >> 4, tx = tid & 15;
    const int m0 = blockIdx.x * 64;
    const int n0 = blockIdx.y * 64;
    const int lr = tid >> 2;
    const int lc = (tid & 3) << 2;
    float acc[4][4] = {};

    for (int k0 = 0; k0 < 512; k0 += 16) {
        float av[4], bv[4];
        load4(&A[(size_t)(m0 + lr) * 512 + k0 + lc], av);
        load4(&W[(size_t)(n0 + lr) * 512 + k0 + lc], bv);
        As[lr][lc + 0] = av[0]; As[lr][lc + 1] = av[1];
        As[lr][lc + 2] = av[2]; As[lr][lc + 3] = av[3];
        Bs[lr][lc + 0] = bv[0]; Bs[lr][lc + 1] = bv[1];
        Bs[lr][lc + 2] = bv[2]; Bs[lr][lc + 3] = bv[3];
        __syncthreads();
        #pragma unroll
        for (int kk = 0; kk < 16; ++kk) {
            float a[4], b[4];
            #pragma unroll
            for (int i = 0; i < 4; ++i) a[i] = As[ty * 4 + i][kk];
            #pragma unroll
            for (int j = 0; j < 4; ++j) b[j] = Bs[tx * 4 + j][kk];
            #pragma unroll
            for (int i = 0; i < 4; ++i)
                #pragma unroll
                for (int j = 0; j < 4; ++j)
                    acc[i][j] += a[i] * b[j];
        }
        __syncthreads();
    }

    #pragma unroll
    for (int i = 0; i < 4; ++i) {
        const int m = m0 + ty * 4 + i;
        #pragma unroll
        for (int j = 0; j < 4; ++j) {
            const int col = n0 + tx * 4 + j;
            float r = acc[i][j];
            if (bias) r += bias[col];
            store1(&out[(size_t)m * 512 + col], r);
        }
    }
}

// ---------------------------------------------------------------------------
// Adaptive avg-pool x (b,56,56,c) fp32 -> x_pool (b,144,c) bf16.
// ---------------------------------------------------------------------------
__global__ __launch_bounds__(256) void pool_x_kernel(
    const float* __restrict__ x, u16* __restrict__ x_pool)
{
    const int b = blockIdx.x, pq = blockIdx.y;
    const int p = pq / PS, qq = pq % PS;
    const int sp_ = (p * HHW) / PS, ep_ = ((p + 1) * HHW + PS - 1) / PS;
    const int sq_ = (qq * HHW) / PS, eq_ = ((qq + 1) * HHW + PS - 1) / PS;
    const float inv = 1.0f / (float)((ep_ - sp_) * (eq_ - sq_));
    for (int ch = threadIdx.x; ch < CHN; ch += 256) {
        float acc = 0.f;
        for (int y = sp_; y < ep_; ++y)
            for (int xx = sq_; xx < eq_; ++xx)
                acc += x[((size_t)b * NTOK + y * HHW + xx) * CHN + ch];
        x_pool[((size_t)b * NAG + pq) * CHN + ch] = f2b(acc * inv);
    }
}

// ---------------------------------------------------------------------------
// Stage-1 flash attention. Block = (agent-tile at, head h, batch b).
// 36 agents/block, 256 threads = 4 waves; wave grp owns agents a0=9*grp..+8
// in BOTH phases, so running m/l/O and alpha stay in registers.
// Per 64-key tile: stage K/V (bf16) -> LDS, S = A.K^T (key=lane),
// wave-butterfly online softmax, P -> LDS, PV (dim=lane).
// ---------------------------------------------------------------------------
__global__ __launch_bounds__(256) void stage1_flash_kernel(
    const u16* __restrict__ k, const u16* __restrict__ v,
    const u16* __restrict__ agent, u16* __restrict__ agent_v)
{
    __shared__ u16   Ks[TK * KPITCH];
    __shared__ u16   Vs[TK * KPITCH];
    __shared__ float As[36 * 64];
    __shared__ float Ps[36 * 64];

    const int at  = blockIdx.x;     // 0..3  -> agents at*36 .. +35
    const int h   = blockIdx.y;
    const int b   = blockIdx.z;
    const int tid = threadIdx.x;
    const int lane = tid & 63;
    const int grp  = tid >> 6;      // 0..3
    const int a0   = grp * 9;       // local agent base for this wave

    // load + scale agent fragment (36 x 64)
    {
        const u16* ab = agent + ((size_t)b * NAG + at * 36) * CHN + h * HD;
        for (int idx = tid; idx < 36 * 64; idx += 256) {
            const int a = idx >> 6, d = idx & 63;
            As[a * 64 + d] = b2f(ab[(size_t)a * CHN + d]) * 0.125f;
        }
    }

    float m_[9], l_[9], o_[9];
    #pragma unroll
    for (int i = 0; i < 9; ++i) { m_[i] = -1e30f; l_[i] = 0.f; o_[i] = 0.f; }

    const int r   = tid >> 2;           // staging row 0..63
    const int d0s = (tid & 3) * 16;     // staging dim offset
    const u16* kp = k + (size_t)b * NTOK * CHN + h * HD;
    const u16* vp = v + (size_t)b * NTOK * CHN + h * HD;

    for (int key0 = 0; key0 < NTOK; key0 += TK) {
        __syncthreads();                 // Ks/Vs/Ps free (prev PV done)
        // ---- stage K/V tile (bf16, coalesced ushort4) ----
        {
            const u16* krow = kp + (size_t)(key0 + r) * CHN + d0s;
            const u16* vrow = vp + (size_t)(key0 + r) * CHN + d0s;
            #pragma unroll
            for (int c = 0; c < 4; ++c) {
                ushort4 kv = *reinterpret_cast<const ushort4*>(krow + c * 4);
                ushort4 vv = *reinterpret_cast<const ushort4*>(vrow + c * 4);
                *reinterpret_cast<ushort4*>(&Ks[r * KPITCH + d0s + c * 4]) = kv;
                *reinterpret_cast<ushort4*>(&Vs[r * KPITCH + d0s + c * 4]) = vv;
            }
        }
        __syncthreads();

        // ---- S: key = lane, 9 agents per thread ----
        float s_[9];
        #pragma unroll
        for (int i = 0; i < 9; ++i) s_[i] = 0.f;
        #pragma unroll 4
        for (int d0 = 0; d0 < 64; d0 += 4) {
            ushort4 kq4 = *reinterpret_cast<const ushort4*>(&Ks[lane * KPITCH + d0]);
            const float k0f = b2f(kq4.x), k1f = b2f(kq4.y),
                        k2f = b2f(kq4.z), k3f = b2f(kq4.w);
            #pragma unroll
            for (int i = 0; i < 9; ++i) {
                float4 a4 = *reinterpret_cast<const float4*>(&As[(a0 + i) * 64 + d0]);
                s_[i] += a4.x * k0f + a4.y * k1f + a4.z * k2f + a4.w * k3f;
            }
        }

        // ---- online softmax (wave-butterfly over the 64 keys) ----
        #pragma unroll
        for (int i = 0; i < 9; ++i) {
            float tmax = s_[i];
            #pragma unroll
            for (int off = 32; off > 0; off >>= 1)
                tmax = fmaxf(tmax, __shfl_xor(tmax, off));
            const float mnew  = fmaxf(m_[i], tmax);
            const float alpha = __expf(m_[i] - mnew);
            const float p     = __expf(s_[i] - mnew);
            float psum = p;
            #pragma unroll
            for (int off = 32; off > 0; off >>= 1)
                psum += __shfl_xor(psum, off);
            l_[i] = l_[i] * alpha + psum;
            m_[i] = mnew;
            o_[i] *= alpha;                       // rescale O (dim=lane mapping)
            Ps[(a0 + i) * 64 + lane] = p;
        }
        __syncthreads();

        // ---- PV: dim = lane, same 9 agents ----
        #pragma unroll 4
        for (int k0 = 0; k0 < TK; k0 += 4) {
            const float v0 = b2f(Vs[(k0 + 0) * KPITCH + lane]);
            const float v1 = b2f(Vs[(k0 + 1) * KPITCH + lane]);
            const float v2 = b2f(Vs[(k0 + 2) * KPITCH + lane]);
            const float v3 = b2f(Vs[(k0 + 3) * KPITCH + lane]);
            #pragma unroll
            for (int i = 0; i < 9; ++i) {
                float4 p4 = *reinterpret_cast<const float4*>(&Ps[(a0 + i) * 64 + k0]);
                o_[i] += p4.x * v0 + p4.y * v1 + p4.z * v2 + p4.w * v3;
            }
        }
    }

    // ---- epilogue ----
    u16* avo = agent_v + (((size_t)b * NH + h) * NAG + at * 36 + a0) * HD + lane;
    #pragma unroll
    for (int i = 0; i < 9; ++i)
        avo[(size_t)i * HD] = f2b(o_[i] / l_[i]);
}

// ---------------------------------------------------------------------------
// Stage-2 attention + fused depthwise 3x3 conv residual.
// One 512-thread block per (b, query i); wave = head; channel = tid.
// ---------------------------------------------------------------------------
__global__ __launch_bounds__(512) void stage2_kernel(
    const u16* __restrict__ q,
    const u16* __restrict__ agent,
    const u16* __restrict__ agent_v,
    const u16* __restrict__ v,
    const float* __restrict__ dwc_w,
    const float* __restrict__ dwc_b,
    u16* __restrict__ xattn)
{
    __shared__ float qrow[CHN];
    __shared__ float sp[NH][NAG];

    const int bi = blockIdx.x;            // b*3136 + i
    const int b = bi / NTOK;
    const int i = bi % NTOK;
    const int tid = threadIdx.x;
    const int h = tid >> 6, dim = tid & 63;

    qrow[tid] = b2f(q[(size_t)bi * CHN + tid]) * 0.125f;
    __syncthreads();

    float s[3];
    #pragma unroll
    for (int slot = 0; slot < 3; ++slot) {
        const int a = dim + slot * 64;
        float acc = -1e30f;
        if (a < NAG) {
            const ushort4* ar = reinterpret_cast<const ushort4*>(
                &agent[((size_t)b * NAG + a) * CHN + h * HD]);
            acc = 0.f;
            #pragma unroll
            for (int t4 = 0; t4 < 16; ++t4) {
                ushort4 av = ar[t4];
                acc += qrow[h * HD + t4 * 4 + 0] * b2f(av.x) + qrow[h * HD + t4 * 4 + 1] * b2f(av.y)
                     + qrow[h * HD + t4 * 4 + 2] * b2f(av.z) + qrow[h * HD + t4 * 4 + 3] * b2f(av.w);
            }
        }
        s[slot] = acc;
    }
    float m = fmaxf(fmaxf(s[0], s[1]), s[2]);
    #pragma unroll
    for (int off = 32; off > 0; off >>= 1) m = fmaxf(m, __shfl_xor(m, off));
    float e0 = __expf(s[0] - m);
    float e1 = __expf(s[1] - m);
    float e2 = (dim < NAG - 128) ? __expf(s[2] - m) : 0.f;
    float lsum = e0 + e1 + e2;
    #pragma unroll
    for (int off = 32; off > 0; off >>= 1) lsum += __shfl_xor(lsum, off);
    const float inv = 1.f / lsum;
    sp[h][dim] = e0 * inv;
    sp[h][dim + 64] = e1 * inv;
    if (dim < NAG - 128) sp[h][dim + 128] = e2 * inv;
    __syncthreads();

    float outv = 0.f;
    const u16* avr = &agent_v[(((size_t)b * NH + h) * NAG) * HD + dim];
    #pragma unroll 4
    for (int a = 0; a < NAG; ++a) outv += sp[h][a] * b2f(avr[(size_t)a * HD]);

    // fused depthwise 3x3 SAME conv on v (+bias), channel = tid
    const int y = i / HHW, xx = i % HHW;
    float conv = dwc_b[tid];
    #pragma unroll
    for (int dy = -1; dy <= 1; ++dy) {
        const int yy = y + dy;
        if (yy < 0 || yy >= HHW) continue;
        #pragma unroll
        for (int dx = -1; dx <= 1; ++dx) {
            const int xc = xx + dx;
            if (xc < 0 || xc >= HHW) continue;
            conv += b2f(v[((size_t)b * NTOK + yy * HHW + xc) * CHN + tid])
                  * dwc_w[tid * 9 + (dy + 1) * 3 + (dx + 1)];
        }
    }

    xattn[(size_t)bi * CHN + tid] = f2b(outv + conv);
}

// ---------------------------------------------------------------------------
extern "C" void kernel_launch(void* const* d_in, const int* in_sizes, int n_in,
                              void* d_out, int out_size, void* d_ws, size_t ws_size,
                              hipStream_t stream)
{
    const float* x      = (const float*)d_in[0];
    const float* qkv_w  = (const float*)d_in[1];
    const float* proj_w = (const float*)d_in[2];
    const float* proj_b = (const float*)d_in[3];
    const float* dwc_w  = (const float*)d_in[4];
    const float* dwc_b  = (const float*)d_in[5];
    float* out = (float*)d_out;

    // d_out (102.7 MB fp32) doubles as bf16 scratch: k | v. q overwrites k
    // after stage-1; final fp32 proj output overwrites all (k,q,v dead).
    const size_t nqkv = (size_t)BATCH * NTOK * CHN;       // 25,690,112
    u16* kq = (u16*)d_out;            // k, later q
    u16* vb = kq + nqkv;              // v
    // attn (bf16) -> x's buffer (x dead after q-GEMM; harness restores inputs)
    u16* xattn = (u16*)d_in[0];

    // ws: x_pool + agent + agent_v, bf16, 3 x 2,359,296 B = 7,077,888 B.
    char* p = (char*)d_ws;
    u16* x_pool  = (u16*)p;  p += (size_t)BATCH * NAG * CHN * 2;
    u16* agent   = (u16*)p;  p += (size_t)BATCH * NAG * CHN * 2;
    u16* agent_v = (u16*)p;

    const float* Wq = qkv_w;
    const float* Wk = qkv_w + (size_t)512 * 512;
    const float* Wv = qkv_w + (size_t)1024 * 512;

    // 1. pooled x (pooling is linear: agent = pool(x) @ Wq^T)
    pool_x_kernel<<<dim3(BATCH, NAG), 256, 0, stream>>>(x, x_pool);
    // 2. agent = x_pool @ Wq^T   (M = 2304)
    gemm64_kernel<u16, u16><<<dim3(36, 8), 256, 0, stream>>>(x_pool, Wq, nullptr, agent);
    // 3. k = x @ Wk^T -> d_out lower half
    gemm64_kernel<float, u16><<<dim3(784, 8), 256, 0, stream>>>(x, Wk, nullptr, kq);
    // 4. v = x @ Wv^T -> d_out upper half
    gemm64_kernel<float, u16><<<dim3(784, 8), 256, 0, stream>>>(x, Wv, nullptr, vb);
    // 5. stage-1 flash attention
    stage1_flash_kernel<<<dim3(4, NH, BATCH), 256, 0, stream>>>(kq, vb, agent, agent_v);
    // 6. q = x @ Wq^T -> d_out lower half (k dead)
    gemm64_kernel<float, u16><<<dim3(784, 8), 256, 0, stream>>>(x, Wq, nullptr, kq);
    // 7. stage-2 + depthwise conv -> xattn (x buffer; x dead afterwards)
    stage2_kernel<<<BATCH * NTOK, 512, 0, stream>>>(kq, agent, agent_v, vb, dwc_w, dwc_b, xattn);
    // 8. out = attn @ proj_w^T + proj_b -> d_out fp32 (q, v dead)
    gemm64_kernel<u16, float><<<dim3(784, 8), 256, 0, stream>>>(xattn, proj_w, proj_b, out);
}

// Round 6
// 3356.771 us; speedup vs baseline: 2.6568x; 1.6454x over previous
//
#include <hip/hip_runtime.h>
#include <hip/hip_bf16.h>
#include <math.h>

typedef unsigned short u16;
typedef __attribute__((ext_vector_type(8))) unsigned short u16x8;

#define BATCH 16
#define NTOK  3136
#define CHN   512
#define NH    8
#define HD    64
#define HHW   56
#define NAG   144
#define PS    12

#define TK     64      // key tile for flash stage-1
#define KPITCH 66      // u16 pitch for stage-1 Ks/Vs

#define QT     64      // queries per stage-2 block
#define APITCH 72      // u16 pitch (144 B rows, 16B-aligned) for Qs/As/AVs
#define PPITCH 152     // u16 pitch for Ps

__device__ __forceinline__ float b2f(u16 u) {
    unsigned int x = ((unsigned int)u) << 16;
    float f;
    __builtin_memcpy(&f, &x, 4);
    return f;
}
__device__ __forceinline__ u16 f2b(float f) {
    unsigned int x;
    __builtin_memcpy(&x, &f, 4);
    unsigned int lsb = (x >> 16) & 1u;
    x += 0x7fffu + lsb;            // round-to-nearest-even (finite values)
    return (u16)(x >> 16);
}

// load 4 consecutive elements as floats
__device__ __forceinline__ void load4(const float* p, float* d) {
    float4 v = *reinterpret_cast<const float4*>(p);
    d[0] = v.x; d[1] = v.y; d[2] = v.z; d[3] = v.w;
}
__device__ __forceinline__ void load4(const u16* p, float* d) {
    ushort4 v = *reinterpret_cast<const ushort4*>(p);
    d[0] = b2f(v.x); d[1] = b2f(v.y); d[2] = b2f(v.z); d[3] = b2f(v.w);
}
__device__ __forceinline__ void store1(float* p, float v) { *p = v; }
__device__ __forceinline__ void store1(u16* p, float v)   { *p = f2b(v); }

// ---------------------------------------------------------------------------
// out[m,n] = A[m,:] . W[n,:] (+ optional bias). 64x64 tile, fp32 FMA.
// ---------------------------------------------------------------------------
template <typename AT, typename OT>
__global__ __launch_bounds__(256) void gemm64_kernel(
    const AT* __restrict__ A, const float* __restrict__ W,
    const float* __restrict__ bias, OT* __restrict__ out)
{
    __shared__ float As[64][17];
    __shared__ float Bs[64][17];
    const int tid = threadIdx.x;
    const int ty = tid >> 4, tx = tid & 15;
    const int m0 = blockIdx.x * 64;
    const int n0 = blockIdx.y * 64;
    const int lr = tid >> 2;
    const int lc = (tid & 3) << 2;
    float acc[4][4] = {};

    for (int k0 = 0; k0 < 512; k0 += 16) {
        float av[4], bv[4];
        load4(&A[(size_t)(m0 + lr) * 512 + k0 + lc], av);
        load4(&W[(size_t)(n0 + lr) * 512 + k0 + lc], bv);
        As[lr][lc + 0] = av[0]; As[lr][lc + 1] = av[1];
        As[lr][lc + 2] = av[2]; As[lr][lc + 3] = av[3];
        Bs[lr][lc + 0] = bv[0]; Bs[lr][lc + 1] = bv[1];
        Bs[lr][lc + 2] = bv[2]; Bs[lr][lc + 3] = bv[3];
        __syncthreads();
        #pragma unroll
        for (int kk = 0; kk < 16; ++kk) {
            float a[4], b[4];
            #pragma unroll
            for (int i = 0; i < 4; ++i) a[i] = As[ty * 4 + i][kk];
            #pragma unroll
            for (int j = 0; j < 4; ++j) b[j] = Bs[tx * 4 + j][kk];
            #pragma unroll
            for (int i = 0; i < 4; ++i)
                #pragma unroll
                for (int j = 0; j < 4; ++j)
                    acc[i][j] += a[i] * b[j];
        }
        __syncthreads();
    }

    #pragma unroll
    for (int i = 0; i < 4; ++i) {
        const int m = m0 + ty * 4 + i;
        #pragma unroll
        for (int j = 0; j < 4; ++j) {
            const int col = n0 + tx * 4 + j;
            float r = acc[i][j];
            if (bias) r += bias[col];
            store1(&out[(size_t)m * 512 + col], r);
        }
    }
}

// ---------------------------------------------------------------------------
// Adaptive avg-pool x (b,56,56,c) fp32 -> x_pool (b,144,c) bf16.
// ---------------------------------------------------------------------------
__global__ __launch_bounds__(256) void pool_x_kernel(
    const float* __restrict__ x, u16* __restrict__ x_pool)
{
    const int b = blockIdx.x, pq = blockIdx.y;
    const int p = pq / PS, qq = pq % PS;
    const int sp_ = (p * HHW) / PS, ep_ = ((p + 1) * HHW + PS - 1) / PS;
    const int sq_ = (qq * HHW) / PS, eq_ = ((qq + 1) * HHW + PS - 1) / PS;
    const float inv = 1.0f / (float)((ep_ - sp_) * (eq_ - sq_));
    for (int ch = threadIdx.x; ch < CHN; ch += 256) {
        float acc = 0.f;
        for (int y = sp_; y < ep_; ++y)
            for (int xx = sq_; xx < eq_; ++xx)
                acc += x[((size_t)b * NTOK + y * HHW + xx) * CHN + ch];
        x_pool[((size_t)b * NAG + pq) * CHN + ch] = f2b(acc * inv);
    }
}

// ---------------------------------------------------------------------------
// Stage-1 flash attention (unchanged from round 5 — passed, off the top-5).
// ---------------------------------------------------------------------------
__global__ __launch_bounds__(256) void stage1_flash_kernel(
    const u16* __restrict__ k, const u16* __restrict__ v,
    const u16* __restrict__ agent, u16* __restrict__ agent_v)
{
    __shared__ u16   Ks[TK * KPITCH];
    __shared__ u16   Vs[TK * KPITCH];
    __shared__ float As[36 * 64];
    __shared__ float Ps[36 * 64];

    const int at  = blockIdx.x;
    const int h   = blockIdx.y;
    const int b   = blockIdx.z;
    const int tid = threadIdx.x;
    const int lane = tid & 63;
    const int grp  = tid >> 6;
    const int a0   = grp * 9;

    {
        const u16* ab = agent + ((size_t)b * NAG + at * 36) * CHN + h * HD;
        for (int idx = tid; idx < 36 * 64; idx += 256) {
            const int a = idx >> 6, d = idx & 63;
            As[a * 64 + d] = b2f(ab[(size_t)a * CHN + d]) * 0.125f;
        }
    }

    float m_[9], l_[9], o_[9];
    #pragma unroll
    for (int i = 0; i < 9; ++i) { m_[i] = -1e30f; l_[i] = 0.f; o_[i] = 0.f; }

    const int r   = tid >> 2;
    const int d0s = (tid & 3) * 16;
    const u16* kp = k + (size_t)b * NTOK * CHN + h * HD;
    const u16* vp = v + (size_t)b * NTOK * CHN + h * HD;

    for (int key0 = 0; key0 < NTOK; key0 += TK) {
        __syncthreads();
        {
            const u16* krow = kp + (size_t)(key0 + r) * CHN + d0s;
            const u16* vrow = vp + (size_t)(key0 + r) * CHN + d0s;
            #pragma unroll
            for (int c = 0; c < 4; ++c) {
                ushort4 kv = *reinterpret_cast<const ushort4*>(krow + c * 4);
                ushort4 vv = *reinterpret_cast<const ushort4*>(vrow + c * 4);
                *reinterpret_cast<ushort4*>(&Ks[r * KPITCH + d0s + c * 4]) = kv;
                *reinterpret_cast<ushort4*>(&Vs[r * KPITCH + d0s + c * 4]) = vv;
            }
        }
        __syncthreads();

        float s_[9];
        #pragma unroll
        for (int i = 0; i < 9; ++i) s_[i] = 0.f;
        #pragma unroll 4
        for (int d0 = 0; d0 < 64; d0 += 4) {
            ushort4 kq4 = *reinterpret_cast<const ushort4*>(&Ks[lane * KPITCH + d0]);
            const float k0f = b2f(kq4.x), k1f = b2f(kq4.y),
                        k2f = b2f(kq4.z), k3f = b2f(kq4.w);
            #pragma unroll
            for (int i = 0; i < 9; ++i) {
                float4 a4 = *reinterpret_cast<const float4*>(&As[(a0 + i) * 64 + d0]);
                s_[i] += a4.x * k0f + a4.y * k1f + a4.z * k2f + a4.w * k3f;
            }
        }

        #pragma unroll
        for (int i = 0; i < 9; ++i) {
            float tmax = s_[i];
            #pragma unroll
            for (int off = 32; off > 0; off >>= 1)
                tmax = fmaxf(tmax, __shfl_xor(tmax, off));
            const float mnew  = fmaxf(m_[i], tmax);
            const float alpha = __expf(m_[i] - mnew);
            const float p     = __expf(s_[i] - mnew);
            float psum = p;
            #pragma unroll
            for (int off = 32; off > 0; off >>= 1)
                psum += __shfl_xor(psum, off);
            l_[i] = l_[i] * alpha + psum;
            m_[i] = mnew;
            o_[i] *= alpha;
            Ps[(a0 + i) * 64 + lane] = p;
        }
        __syncthreads();

        #pragma unroll 4
        for (int k0 = 0; k0 < TK; k0 += 4) {
            const float v0 = b2f(Vs[(k0 + 0) * KPITCH + lane]);
            const float v1 = b2f(Vs[(k0 + 1) * KPITCH + lane]);
            const float v2 = b2f(Vs[(k0 + 2) * KPITCH + lane]);
            const float v3 = b2f(Vs[(k0 + 3) * KPITCH + lane]);
            #pragma unroll
            for (int i = 0; i < 9; ++i) {
                float4 p4 = *reinterpret_cast<const float4*>(&Ps[(a0 + i) * 64 + k0]);
                o_[i] += p4.x * v0 + p4.y * v1 + p4.z * v2 + p4.w * v3;
            }
        }
    }

    u16* avo = agent_v + (((size_t)b * NH + h) * NAG + at * 36 + a0) * HD + lane;
    #pragma unroll
    for (int i = 0; i < 9; ++i)
        avo[(size_t)i * HD] = f2b(o_[i] / l_[i]);
}

// ---------------------------------------------------------------------------
// Stage-2 tiled: block = (64-query tile, head, batch), 256 threads.
// LDS-staged agent/agent_v/Q; S = Q.A^T (thread = query x 36-agent group);
// shuffle softmax over the 4 agent-group lanes; P -> LDS (bf16, unnormalized,
// 1/l kept in registers); PV (thread = query x 16-dim group); fused depthwise
// 3x3 conv; coalesced bf16 stores.
// ---------------------------------------------------------------------------
__global__ __launch_bounds__(256) void stage2_tiled_kernel(
    const u16* __restrict__ q,
    const u16* __restrict__ agent,
    const u16* __restrict__ agent_v,
    const u16* __restrict__ v,
    const float* __restrict__ dwc_w,
    const float* __restrict__ dwc_b,
    u16* __restrict__ xattn)
{
    __shared__ u16 Qs[QT * APITCH];        //  9216 B
    __shared__ u16 As[NAG * APITCH];       // 20736 B
    __shared__ u16 AVs[NAG * APITCH];      // 20736 B
    __shared__ u16 Ps[QT * PPITCH];        // 19456 B
    __shared__ float dwW[HD * 9];          //  2304 B
    __shared__ float dwB[HD];              //   256 B   (total 72,704 B)

    const int qt  = blockIdx.x;            // 0..48
    const int h   = blockIdx.y;
    const int b   = blockIdx.z;
    const int tid = threadIdx.x;
    const int ql  = tid >> 2;              // local query 0..63
    const int ag  = tid & 3;               // agent group (S phase)
    const int d0  = (tid & 3) * 16;        // dim group (PV phase)

    // ---- stage Q tile / agent / agent_v / dwc ----
    const u16* qbase = q + ((size_t)b * NTOK + qt * QT) * CHN + h * HD;
    for (int idx = tid; idx < QT * 16; idx += 256) {
        const int r = idx >> 4, c = (idx & 15) * 4;
        ushort4 t = *reinterpret_cast<const ushort4*>(qbase + (size_t)r * CHN + c);
        *reinterpret_cast<ushort4*>(&Qs[r * APITCH + c]) = t;
    }
    const u16* abase = agent + (size_t)b * NAG * CHN + h * HD;
    for (int idx = tid; idx < NAG * 16; idx += 256) {
        const int r = idx >> 4, c = (idx & 15) * 4;
        ushort4 t = *reinterpret_cast<const ushort4*>(abase + (size_t)r * CHN + c);
        *reinterpret_cast<ushort4*>(&As[r * APITCH + c]) = t;
    }
    const u16* avbase = agent_v + ((size_t)b * NH + h) * NAG * HD;
    for (int idx = tid; idx < NAG * 16; idx += 256) {
        const int r = idx >> 4, c = (idx & 15) * 4;
        ushort4 t = *reinterpret_cast<const ushort4*>(avbase + (size_t)r * HD + c);
        *reinterpret_cast<ushort4*>(&AVs[r * APITCH + c]) = t;
    }
    for (int idx = tid; idx < HD * 9; idx += 256)
        dwW[idx] = dwc_w[(h * HD + idx / 9) * 9 + (idx % 9)];
    if (tid < HD) dwB[tid] = dwc_b[h * HD + tid];
    __syncthreads();

    // ---- S phase: 36 agents per thread ----
    const int a0 = ag * 36;
    float s_[36];
    #pragma unroll
    for (int i = 0; i < 36; ++i) s_[i] = 0.f;
    for (int dd = 0; dd < HD; dd += 8) {
        u16x8 qv = *reinterpret_cast<const u16x8*>(&Qs[ql * APITCH + dd]);
        float qf[8];
        #pragma unroll
        for (int j = 0; j < 8; ++j) qf[j] = b2f(qv[j]);
        #pragma unroll
        for (int i = 0; i < 36; ++i) {
            u16x8 av = *reinterpret_cast<const u16x8*>(&As[(a0 + i) * APITCH + dd]);
            float t = 0.f;
            #pragma unroll
            for (int j = 0; j < 8; ++j) t += qf[j] * b2f(av[j]);
            s_[i] += t;
        }
    }

    // softmax over 144 (4 adjacent lanes hold the 4 agent groups of a query)
    float mx = -1e30f;
    #pragma unroll
    for (int i = 0; i < 36; ++i) { s_[i] *= 0.125f; mx = fmaxf(mx, s_[i]); }
    mx = fmaxf(mx, __shfl_xor(mx, 1));
    mx = fmaxf(mx, __shfl_xor(mx, 2));
    float ls = 0.f;
    #pragma unroll
    for (int i = 0; i < 36; ++i) { float e = __expf(s_[i] - mx); s_[i] = e; ls += e; }
    ls += __shfl_xor(ls, 1);
    ls += __shfl_xor(ls, 2);
    const float inv = 1.f / ls;
    #pragma unroll
    for (int i = 0; i < 36; ++i) Ps[ql * PPITCH + a0 + i] = f2b(s_[i]);
    __syncthreads();

    // ---- PV phase: 16 dims per thread ----
    float acc[16];
    #pragma unroll
    for (int j = 0; j < 16; ++j) acc[j] = 0.f;
    for (int a = 0; a < NAG; ++a) {
        const float pw = b2f(Ps[ql * PPITCH + a]);
        u16x8 v0 = *reinterpret_cast<const u16x8*>(&AVs[a * APITCH + d0]);
        u16x8 v1 = *reinterpret_cast<const u16x8*>(&AVs[a * APITCH + d0 + 8]);
        #pragma unroll
        for (int j = 0; j < 8; ++j) acc[j]     += pw * b2f(v0[j]);
        #pragma unroll
        for (int j = 0; j < 8; ++j) acc[8 + j] += pw * b2f(v1[j]);
    }

    // ---- fused depthwise conv + store ----
    const int qg = qt * QT + ql;
    const int y = qg / HHW, xx = qg % HHW;
    float res[16];
    #pragma unroll
    for (int j = 0; j < 16; ++j) res[j] = acc[j] * inv + dwB[d0 + j];
    const u16* vq = v + ((size_t)b * NTOK + qg) * CHN + h * HD + d0;
    #pragma unroll
    for (int dy = -1; dy <= 1; ++dy) {
        const int yy = y + dy;
        if (yy < 0 || yy >= HHW) continue;
        #pragma unroll
        for (int dx = -1; dx <= 1; ++dx) {
            const int xc = xx + dx;
            if (xc < 0 || xc >= HHW) continue;
            const int tap = (dy + 1) * 3 + (dx + 1);
            const u16* vr = vq + (ptrdiff_t)(dy * HHW + dx) * CHN;
            #pragma unroll
            for (int c = 0; c < 4; ++c) {
                ushort4 vv = *reinterpret_cast<const ushort4*>(vr + c * 4);
                res[c * 4 + 0] += b2f(vv.x) * dwW[(d0 + c * 4 + 0) * 9 + tap];
                res[c * 4 + 1] += b2f(vv.y) * dwW[(d0 + c * 4 + 1) * 9 + tap];
                res[c * 4 + 2] += b2f(vv.z) * dwW[(d0 + c * 4 + 2) * 9 + tap];
                res[c * 4 + 3] += b2f(vv.w) * dwW[(d0 + c * 4 + 3) * 9 + tap];
            }
        }
    }

    u16* outp = xattn + ((size_t)b * NTOK + qg) * CHN + h * HD + d0;
    #pragma unroll
    for (int c = 0; c < 4; ++c) {
        ushort4 o;
        o.x = f2b(res[c * 4 + 0]); o.y = f2b(res[c * 4 + 1]);
        o.z = f2b(res[c * 4 + 2]); o.w = f2b(res[c * 4 + 3]);
        *reinterpret_cast<ushort4*>(outp + c * 4) = o;
    }
}

// ---------------------------------------------------------------------------
extern "C" void kernel_launch(void* const* d_in, const int* in_sizes, int n_in,
                              void* d_out, int out_size, void* d_ws, size_t ws_size,
                              hipStream_t stream)
{
    const float* x      = (const float*)d_in[0];
    const float* qkv_w  = (const float*)d_in[1];
    const float* proj_w = (const float*)d_in[2];
    const float* proj_b = (const float*)d_in[3];
    const float* dwc_w  = (const float*)d_in[4];
    const float* dwc_b  = (const float*)d_in[5];
    float* out = (float*)d_out;

    // d_out (102.7 MB fp32) doubles as bf16 scratch: k | v. q overwrites k
    // after stage-1; final fp32 proj output overwrites all (k,q,v dead).
    const size_t nqkv = (size_t)BATCH * NTOK * CHN;       // 25,690,112
    u16* kq = (u16*)d_out;            // k, later q
    u16* vb = kq + nqkv;              // v
    // attn (bf16) -> x's buffer (x dead after q-GEMM; harness restores inputs)
    u16* xattn = (u16*)d_in[0];

    // ws: x_pool + agent + agent_v, bf16, 3 x 2,359,296 B = 7,077,888 B.
    char* p = (char*)d_ws;
    u16* x_pool  = (u16*)p;  p += (size_t)BATCH * NAG * CHN * 2;
    u16* agent   = (u16*)p;  p += (size_t)BATCH * NAG * CHN * 2;
    u16* agent_v = (u16*)p;

    const float* Wq = qkv_w;
    const float* Wk = qkv_w + (size_t)512 * 512;
    const float* Wv = qkv_w + (size_t)1024 * 512;

    // 1. pooled x (pooling is linear: agent = pool(x) @ Wq^T)
    pool_x_kernel<<<dim3(BATCH, NAG), 256, 0, stream>>>(x, x_pool);
    // 2. agent = x_pool @ Wq^T   (M = 2304)
    gemm64_kernel<u16, u16><<<dim3(36, 8), 256, 0, stream>>>(x_pool, Wq, nullptr, agent);
    // 3. k = x @ Wk^T -> d_out lower half
    gemm64_kernel<float, u16><<<dim3(784, 8), 256, 0, stream>>>(x, Wk, nullptr, kq);
    // 4. v = x @ Wv^T -> d_out upper half
    gemm64_kernel<float, u16><<<dim3(784, 8), 256, 0, stream>>>(x, Wv, nullptr, vb);
    // 5. stage-1 flash attention
    stage1_flash_kernel<<<dim3(4, NH, BATCH), 256, 0, stream>>>(kq, vb, agent, agent_v);
    // 6. q = x @ Wq^T -> d_out lower half (k dead)
    gemm64_kernel<float, u16><<<dim3(784, 8), 256, 0, stream>>>(x, Wq, nullptr, kq);
    // 7. stage-2 tiled + depthwise conv -> xattn (x buffer; x dead afterwards)
    stage2_tiled_kernel<<<dim3(49, NH, BATCH), 256, 0, stream>>>(
        kq, agent, agent_v, vb, dwc_w, dwc_b, xattn);
    // 8. out = attn @ proj_w^T + proj_b -> d_out fp32 (q, v dead)
    gemm64_kernel<u16, float><<<dim3(784, 8), 256, 0, stream>>>(xattn, proj_w, proj_b, out);
}

// Round 7
// 1497.338 us; speedup vs baseline: 5.9560x; 2.2418x over previous
//
#include <hip/hip_runtime.h>
#include <hip/hip_bf16.h>
#include <math.h>

typedef unsigned short u16;
typedef __attribute__((ext_vector_type(8))) unsigned short u16x8;
typedef __attribute__((ext_vector_type(8))) short bf16x8;
typedef __attribute__((ext_vector_type(4))) float f32x4;

#define BATCH 16
#define NTOK  3136
#define CHN   512
#define NH    8
#define HD    64
#define HHW   56
#define NAG   144
#define PS    12

#define TK     64      // key tile for flash stage-1
#define KPITCH 66      // u16 pitch for stage-1 Ks/Vs

#define QT     64      // queries per stage-2 block
#define APITCH 72      // u16 pitch for stage-2 Qs/As/AVs
#define PPITCH 152     // u16 pitch for stage-2 Ps

__device__ __forceinline__ float b2f(u16 u) {
    unsigned int x = ((unsigned int)u) << 16;
    float f;
    __builtin_memcpy(&f, &x, 4);
    return f;
}
__device__ __forceinline__ u16 f2b(float f) {
    unsigned int x;
    __builtin_memcpy(&x, &f, 4);
    unsigned int lsb = (x >> 16) & 1u;
    x += 0x7fffu + lsb;            // round-to-nearest-even (finite values)
    return (u16)(x >> 16);
}
__device__ __forceinline__ void store1(float* p, float v) { *p = v; }
__device__ __forceinline__ void store1(u16* p, float v)   { *p = f2b(v); }

// ---------------------------------------------------------------------------
// fp32 -> bf16 conversion (vectorized, memory-bound)
// ---------------------------------------------------------------------------
__global__ __launch_bounds__(256) void cvt_f32_bf16_kernel(
    const float* __restrict__ src, u16* __restrict__ dst, int n4)
{
    const int idx = blockIdx.x * 256 + threadIdx.x;
    if (idx >= n4) return;
    float4 v = reinterpret_cast<const float4*>(src)[idx];
    ushort4 o;
    o.x = f2b(v.x); o.y = f2b(v.y); o.z = f2b(v.z); o.w = f2b(v.w);
    reinterpret_cast<ushort4*>(dst)[idx] = o;
}

// ---------------------------------------------------------------------------
// MFMA GEMM (m97 pattern): out[m,n] = A[m,:].W[n,:] (+bias), K=512, N=512.
// A: M x 512 bf16 row-major; W: 512 x 512 bf16 row-major (B^T layout).
// Grid (M/128, 4), 256 thr = 4 waves in 2x2; each wave 64x64 via 4x4
// mfma_f32_16x16x32_bf16 tiles. global_load_lds width=16 staging, BK=64.
// ---------------------------------------------------------------------------
template <typename OT, bool BIAS>
__global__ __launch_bounds__(256) void mfma_gemm_kernel(
    const u16* __restrict__ A, const u16* __restrict__ W,
    const float* __restrict__ bias, OT* __restrict__ out)
{
    __shared__ u16 Asm[128 * 64];
    __shared__ u16 Bsm[128 * 64];

    const int tid  = threadIdx.x;
    const int lane = tid & 63;
    const int w    = tid >> 6;          // wave 0..3
    const int m0   = blockIdx.x * 128;
    const int n0   = blockIdx.y * 128;
    const int wm   = (w & 1) * 64;      // wave row offset in tile
    const int wn   = (w >> 1) * 64;     // wave col offset in tile

    const int srow = lane >> 3;         // staging row within 8-row chunk
    const int scol = (lane & 7) * 8;    // staging k-offset (elems)

    f32x4 acc[4][4] = {};

    for (int kt = 0; kt < 8; ++kt) {
        const int k0 = kt * 64;
        __syncthreads();                 // LDS free (prev iter's reads done)
        #pragma unroll
        for (int i = 0; i < 4; ++i) {
            const int rb = w * 8 + i * 32;
            __builtin_amdgcn_global_load_lds(
                (const __attribute__((address_space(1))) void*)
                    (A + (size_t)(m0 + rb + srow) * 512 + k0 + scol),
                (__attribute__((address_space(3))) void*)(Asm + rb * 64),
                16, 0, 0);
        }
        #pragma unroll
        for (int i = 0; i < 4; ++i) {
            const int rb = w * 8 + i * 32;
            __builtin_amdgcn_global_load_lds(
                (const __attribute__((address_space(1))) void*)
                    (W + (size_t)(n0 + rb + srow) * 512 + k0 + scol),
                (__attribute__((address_space(3))) void*)(Bsm + rb * 64),
                16, 0, 0);
        }
        __syncthreads();                 // staging complete

        #pragma unroll
        for (int kh = 0; kh < 2; ++kh) {
            bf16x8 af[4], bfr[4];
            #pragma unroll
            for (int t = 0; t < 4; ++t)
                af[t] = *reinterpret_cast<const bf16x8*>(
                    &Asm[(wm + t * 16 + (lane & 15)) * 64 + kh * 32 + (lane >> 4) * 8]);
            #pragma unroll
            for (int t = 0; t < 4; ++t)
                bfr[t] = *reinterpret_cast<const bf16x8*>(
                    &Bsm[(wn + t * 16 + (lane & 15)) * 64 + kh * 32 + (lane >> 4) * 8]);
            #pragma unroll
            for (int i = 0; i < 4; ++i)
                #pragma unroll
                for (int j = 0; j < 4; ++j)
                    acc[i][j] = __builtin_amdgcn_mfma_f32_16x16x32_bf16(
                        af[i], bfr[j], acc[i][j], 0, 0, 0);
        }
    }

    // epilogue: C/D layout col=lane&15, row=(lane>>4)*4+reg  [m89/m91]
    const int quad = lane >> 4;
    const int col  = lane & 15;
    #pragma unroll
    for (int j = 0; j < 4; ++j) {
        const int n = n0 + wn + j * 16 + col;
        const float bv = BIAS ? bias[n] : 0.f;
        #pragma unroll
        for (int i = 0; i < 4; ++i) {
            #pragma unroll
            for (int r = 0; r < 4; ++r) {
                const int m = m0 + wm + i * 16 + quad * 4 + r;
                store1(&out[(size_t)m * 512 + n], acc[i][j][r] + bv);
            }
        }
    }
}

// ---------------------------------------------------------------------------
// Adaptive avg-pool x (b,56,56,c) fp32 -> x_pool (b,144,c) bf16.
// ---------------------------------------------------------------------------
__global__ __launch_bounds__(256) void pool_x_kernel(
    const float* __restrict__ x, u16* __restrict__ x_pool)
{
    const int b = blockIdx.x, pq = blockIdx.y;
    const int p = pq / PS, qq = pq % PS;
    const int sp_ = (p * HHW) / PS, ep_ = ((p + 1) * HHW + PS - 1) / PS;
    const int sq_ = (qq * HHW) / PS, eq_ = ((qq + 1) * HHW + PS - 1) / PS;
    const float inv = 1.0f / (float)((ep_ - sp_) * (eq_ - sq_));
    for (int ch = threadIdx.x; ch < CHN; ch += 256) {
        float acc = 0.f;
        for (int y = sp_; y < ep_; ++y)
            for (int xx = sq_; xx < eq_; ++xx)
                acc += x[((size_t)b * NTOK + y * HHW + xx) * CHN + ch];
        x_pool[((size_t)b * NAG + pq) * CHN + ch] = f2b(acc * inv);
    }
}

// ---------------------------------------------------------------------------
// Stage-1 flash attention (unchanged — passed, round 5).
// ---------------------------------------------------------------------------
__global__ __launch_bounds__(256) void stage1_flash_kernel(
    const u16* __restrict__ k, const u16* __restrict__ v,
    const u16* __restrict__ agent, u16* __restrict__ agent_v)
{
    __shared__ u16   Ks[TK * KPITCH];
    __shared__ u16   Vs[TK * KPITCH];
    __shared__ float As[36 * 64];
    __shared__ float Ps[36 * 64];

    const int at  = blockIdx.x;
    const int h   = blockIdx.y;
    const int b   = blockIdx.z;
    const int tid = threadIdx.x;
    const int lane = tid & 63;
    const int grp  = tid >> 6;
    const int a0   = grp * 9;

    {
        const u16* ab = agent + ((size_t)b * NAG + at * 36) * CHN + h * HD;
        for (int idx = tid; idx < 36 * 64; idx += 256) {
            const int a = idx >> 6, d = idx & 63;
            As[a * 64 + d] = b2f(ab[(size_t)a * CHN + d]) * 0.125f;
        }
    }

    float m_[9], l_[9], o_[9];
    #pragma unroll
    for (int i = 0; i < 9; ++i) { m_[i] = -1e30f; l_[i] = 0.f; o_[i] = 0.f; }

    const int r   = tid >> 2;
    const int d0s = (tid & 3) * 16;
    const u16* kp = k + (size_t)b * NTOK * CHN + h * HD;
    const u16* vp = v + (size_t)b * NTOK * CHN + h * HD;

    for (int key0 = 0; key0 < NTOK; key0 += TK) {
        __syncthreads();
        {
            const u16* krow = kp + (size_t)(key0 + r) * CHN + d0s;
            const u16* vrow = vp + (size_t)(key0 + r) * CHN + d0s;
            #pragma unroll
            for (int c = 0; c < 4; ++c) {
                ushort4 kv = *reinterpret_cast<const ushort4*>(krow + c * 4);
                ushort4 vv = *reinterpret_cast<const ushort4*>(vrow + c * 4);
                *reinterpret_cast<ushort4*>(&Ks[r * KPITCH + d0s + c * 4]) = kv;
                *reinterpret_cast<ushort4*>(&Vs[r * KPITCH + d0s + c * 4]) = vv;
            }
        }
        __syncthreads();

        float s_[9];
        #pragma unroll
        for (int i = 0; i < 9; ++i) s_[i] = 0.f;
        #pragma unroll 4
        for (int d0 = 0; d0 < 64; d0 += 4) {
            ushort4 kq4 = *reinterpret_cast<const ushort4*>(&Ks[lane * KPITCH + d0]);
            const float k0f = b2f(kq4.x), k1f = b2f(kq4.y),
                        k2f = b2f(kq4.z), k3f = b2f(kq4.w);
            #pragma unroll
            for (int i = 0; i < 9; ++i) {
                float4 a4 = *reinterpret_cast<const float4*>(&As[(a0 + i) * 64 + d0]);
                s_[i] += a4.x * k0f + a4.y * k1f + a4.z * k2f + a4.w * k3f;
            }
        }

        #pragma unroll
        for (int i = 0; i < 9; ++i) {
            float tmax = s_[i];
            #pragma unroll
            for (int off = 32; off > 0; off >>= 1)
                tmax = fmaxf(tmax, __shfl_xor(tmax, off));
            const float mnew  = fmaxf(m_[i], tmax);
            const float alpha = __expf(m_[i] - mnew);
            const float p     = __expf(s_[i] - mnew);
            float psum = p;
            #pragma unroll
            for (int off = 32; off > 0; off >>= 1)
                psum += __shfl_xor(psum, off);
            l_[i] = l_[i] * alpha + psum;
            m_[i] = mnew;
            o_[i] *= alpha;
            Ps[(a0 + i) * 64 + lane] = p;
        }
        __syncthreads();

        #pragma unroll 4
        for (int k0 = 0; k0 < TK; k0 += 4) {
            const float v0 = b2f(Vs[(k0 + 0) * KPITCH + lane]);
            const float v1 = b2f(Vs[(k0 + 1) * KPITCH + lane]);
            const float v2 = b2f(Vs[(k0 + 2) * KPITCH + lane]);
            const float v3 = b2f(Vs[(k0 + 3) * KPITCH + lane]);
            #pragma unroll
            for (int i = 0; i < 9; ++i) {
                float4 p4 = *reinterpret_cast<const float4*>(&Ps[(a0 + i) * 64 + k0]);
                o_[i] += p4.x * v0 + p4.y * v1 + p4.z * v2 + p4.w * v3;
            }
        }
    }

    u16* avo = agent_v + (((size_t)b * NH + h) * NAG + at * 36 + a0) * HD + lane;
    #pragma unroll
    for (int i = 0; i < 9; ++i)
        avo[(size_t)i * HD] = f2b(o_[i] / l_[i]);
}

// ---------------------------------------------------------------------------
// Stage-2 tiled + fused depthwise conv (unchanged — passed, round 6).
// ---------------------------------------------------------------------------
__global__ __launch_bounds__(256) void stage2_tiled_kernel(
    const u16* __restrict__ q,
    const u16* __restrict__ agent,
    const u16* __restrict__ agent_v,
    const u16* __restrict__ v,
    const float* __restrict__ dwc_w,
    const float* __restrict__ dwc_b,
    u16* __restrict__ xattn)
{
    __shared__ u16 Qs[QT * APITCH];
    __shared__ u16 As[NAG * APITCH];
    __shared__ u16 AVs[NAG * APITCH];
    __shared__ u16 Ps[QT * PPITCH];
    __shared__ float dwW[HD * 9];
    __shared__ float dwB[HD];

    const int qt  = blockIdx.x;
    const int h   = blockIdx.y;
    const int b   = blockIdx.z;
    const int tid = threadIdx.x;
    const int ql  = tid >> 2;
    const int ag  = tid & 3;
    const int d0  = (tid & 3) * 16;

    const u16* qbase = q + ((size_t)b * NTOK + qt * QT) * CHN + h * HD;
    for (int idx = tid; idx < QT * 16; idx += 256) {
        const int r = idx >> 4, c = (idx & 15) * 4;
        ushort4 t = *reinterpret_cast<const ushort4*>(qbase + (size_t)r * CHN + c);
        *reinterpret_cast<ushort4*>(&Qs[r * APITCH + c]) = t;
    }
    const u16* abase = agent + (size_t)b * NAG * CHN + h * HD;
    for (int idx = tid; idx < NAG * 16; idx += 256) {
        const int r = idx >> 4, c = (idx & 15) * 4;
        ushort4 t = *reinterpret_cast<const ushort4*>(abase + (size_t)r * CHN + c);
        *reinterpret_cast<ushort4*>(&As[r * APITCH + c]) = t;
    }
    const u16* avbase = agent_v + ((size_t)b * NH + h) * NAG * HD;
    for (int idx = tid; idx < NAG * 16; idx += 256) {
        const int r = idx >> 4, c = (idx & 15) * 4;
        ushort4 t = *reinterpret_cast<const ushort4*>(avbase + (size_t)r * HD + c);
        *reinterpret_cast<ushort4*>(&AVs[r * APITCH + c]) = t;
    }
    for (int idx = tid; idx < HD * 9; idx += 256)
        dwW[idx] = dwc_w[(h * HD + idx / 9) * 9 + (idx % 9)];
    if (tid < HD) dwB[tid] = dwc_b[h * HD + tid];
    __syncthreads();

    const int a0 = ag * 36;
    float s_[36];
    #pragma unroll
    for (int i = 0; i < 36; ++i) s_[i] = 0.f;
    for (int dd = 0; dd < HD; dd += 8) {
        u16x8 qv = *reinterpret_cast<const u16x8*>(&Qs[ql * APITCH + dd]);
        float qf[8];
        #pragma unroll
        for (int j = 0; j < 8; ++j) qf[j] = b2f(qv[j]);
        #pragma unroll
        for (int i = 0; i < 36; ++i) {
            u16x8 av = *reinterpret_cast<const u16x8*>(&As[(a0 + i) * APITCH + dd]);
            float t = 0.f;
            #pragma unroll
            for (int j = 0; j < 8; ++j) t += qf[j] * b2f(av[j]);
            s_[i] += t;
        }
    }

    float mx = -1e30f;
    #pragma unroll
    for (int i = 0; i < 36; ++i) { s_[i] *= 0.125f; mx = fmaxf(mx, s_[i]); }
    mx = fmaxf(mx, __shfl_xor(mx, 1));
    mx = fmaxf(mx, __shfl_xor(mx, 2));
    float ls = 0.f;
    #pragma unroll
    for (int i = 0; i < 36; ++i) { float e = __expf(s_[i] - mx); s_[i] = e; ls += e; }
    ls += __shfl_xor(ls, 1);
    ls += __shfl_xor(ls, 2);
    const float inv = 1.f / ls;
    #pragma unroll
    for (int i = 0; i < 36; ++i) Ps[ql * PPITCH + a0 + i] = f2b(s_[i]);
    __syncthreads();

    float acc[16];
    #pragma unroll
    for (int j = 0; j < 16; ++j) acc[j] = 0.f;
    for (int a = 0; a < NAG; ++a) {
        const float pw = b2f(Ps[ql * PPITCH + a]);
        u16x8 v0 = *reinterpret_cast<const u16x8*>(&AVs[a * APITCH + d0]);
        u16x8 v1 = *reinterpret_cast<const u16x8*>(&AVs[a * APITCH + d0 + 8]);
        #pragma unroll
        for (int j = 0; j < 8; ++j) acc[j]     += pw * b2f(v0[j]);
        #pragma unroll
        for (int j = 0; j < 8; ++j) acc[8 + j] += pw * b2f(v1[j]);
    }

    const int qg = qt * QT + ql;
    const int y = qg / HHW, xx = qg % HHW;
    float res[16];
    #pragma unroll
    for (int j = 0; j < 16; ++j) res[j] = acc[j] * inv + dwB[d0 + j];
    const u16* vq = v + ((size_t)b * NTOK + qg) * CHN + h * HD + d0;
    #pragma unroll
    for (int dy = -1; dy <= 1; ++dy) {
        const int yy = y + dy;
        if (yy < 0 || yy >= HHW) continue;
        #pragma unroll
        for (int dx = -1; dx <= 1; ++dx) {
            const int xc = xx + dx;
            if (xc < 0 || xc >= HHW) continue;
            const int tap = (dy + 1) * 3 + (dx + 1);
            const u16* vr = vq + (ptrdiff_t)(dy * HHW + dx) * CHN;
            #pragma unroll
            for (int c = 0; c < 4; ++c) {
                ushort4 vv = *reinterpret_cast<const ushort4*>(vr + c * 4);
                res[c * 4 + 0] += b2f(vv.x) * dwW[(d0 + c * 4 + 0) * 9 + tap];
                res[c * 4 + 1] += b2f(vv.y) * dwW[(d0 + c * 4 + 1) * 9 + tap];
                res[c * 4 + 2] += b2f(vv.z) * dwW[(d0 + c * 4 + 2) * 9 + tap];
                res[c * 4 + 3] += b2f(vv.w) * dwW[(d0 + c * 4 + 3) * 9 + tap];
            }
        }
    }

    u16* outp = xattn + ((size_t)b * NTOK + qg) * CHN + h * HD + d0;
    #pragma unroll
    for (int c = 0; c < 4; ++c) {
        ushort4 o;
        o.x = f2b(res[c * 4 + 0]); o.y = f2b(res[c * 4 + 1]);
        o.z = f2b(res[c * 4 + 2]); o.w = f2b(res[c * 4 + 3]);
        *reinterpret_cast<ushort4*>(outp + c * 4) = o;
    }
}

// ---------------------------------------------------------------------------
extern "C" void kernel_launch(void* const* d_in, const int* in_sizes, int n_in,
                              void* d_out, int out_size, void* d_ws, size_t ws_size,
                              hipStream_t stream)
{
    const float* x      = (const float*)d_in[0];
    const float* qkv_w  = (const float*)d_in[1];
    const float* proj_w = (const float*)d_in[2];
    const float* proj_b = (const float*)d_in[3];
    const float* dwc_w  = (const float*)d_in[4];
    const float* dwc_b  = (const float*)d_in[5];
    float* out = (float*)d_out;

    const size_t nqkv = (size_t)BATCH * NTOK * CHN;       // 25,690,112
    // Buffer choreography (all race-free by stream order):
    //   d_out.lo: xb (bf16 x), later attn? NO -> xb until q-GEMM, then dead;
    //             final proj writes fp32 over full d_out.
    //   d_out.hi: q (bf16)
    //   x.lo:     k (bf16, after pool+cvt consumed x), then attn (k dead)
    //   x.hi:     v (bf16)
    u16* xb  = (u16*)d_out;           // bf16 x
    u16* qb  = xb + nqkv;             // q
    u16* kb  = (u16*)d_in[0];         // k  (x buffer lower half)
    u16* vb  = kb + nqkv;             // v  (x buffer upper half)
    u16* attn = kb;                   // attn overwrites k (dead after stage1)

    // ws: x_pool/agent/agent_v (3 x 2,359,296 B) + wb (2,097,152 B) = 9.18 MB
    char* p = (char*)d_ws;
    u16* x_pool  = (u16*)p;  p += (size_t)BATCH * NAG * CHN * 2;
    u16* agent   = (u16*)p;  p += (size_t)BATCH * NAG * CHN * 2;
    u16* agent_v = (u16*)p;  p += (size_t)BATCH * NAG * CHN * 2;
    u16* wb      = (u16*)p;           // qkv_w (786432) + proj_w (262144) bf16
    u16* Wq_b = wb;
    u16* Wk_b = wb + (size_t)262144;
    u16* Wv_b = wb + (size_t)524288;
    u16* Wp_b = wb + (size_t)786432;

    // 1. pool x (fp32, exact) -> x_pool bf16      [reads x]
    pool_x_kernel<<<dim3(BATCH, NAG), 256, 0, stream>>>(x, x_pool);
    // 2. convert x -> xb (d_out.lo)               [reads x]
    cvt_f32_bf16_kernel<<<(int)(nqkv / 4 + 255) / 256, 256, 0, stream>>>(x, xb, (int)(nqkv / 4));
    // 3. convert weights -> wb
    cvt_f32_bf16_kernel<<<(786432 / 4 + 255) / 256, 256, 0, stream>>>(qkv_w, wb, 786432 / 4);
    cvt_f32_bf16_kernel<<<(262144 / 4 + 255) / 256, 256, 0, stream>>>(proj_w, Wp_b, 262144 / 4);
    // 4. agent = x_pool @ Wq^T  (M = 2304)
    mfma_gemm_kernel<u16, false><<<dim3(18, 4), 256, 0, stream>>>(x_pool, Wq_b, nullptr, agent);
    // 5. k = xb @ Wk^T -> x.lo  (x fp32 fully consumed by 1&2)
    mfma_gemm_kernel<u16, false><<<dim3(392, 4), 256, 0, stream>>>(xb, Wk_b, nullptr, kb);
    // 6. v = xb @ Wv^T -> x.hi
    mfma_gemm_kernel<u16, false><<<dim3(392, 4), 256, 0, stream>>>(xb, Wv_b, nullptr, vb);
    // 7. stage-1 flash attention
    stage1_flash_kernel<<<dim3(4, NH, BATCH), 256, 0, stream>>>(kb, vb, agent, agent_v);
    // 8. q = xb @ Wq^T -> d_out.hi  (xb dead afterwards)
    mfma_gemm_kernel<u16, false><<<dim3(392, 4), 256, 0, stream>>>(xb, Wq_b, nullptr, qb);
    // 9. stage-2 tiled + dw conv -> attn (x.lo; k dead, disjoint from q/v)
    stage2_tiled_kernel<<<dim3(49, NH, BATCH), 256, 0, stream>>>(
        qb, agent, agent_v, vb, dwc_w, dwc_b, attn);
    // 10. out = attn @ proj_w^T + proj_b -> full d_out fp32 (xb,q dead)
    mfma_gemm_kernel<float, true><<<dim3(392, 4), 256, 0, stream>>>(attn, Wp_b, proj_b, out);
}